// Round 23
// baseline (104.681 us; speedup 1.0000x reference)
//
#include <hip/hip_runtime.h>
#include <hip/hip_bf16.h>

typedef _Float16 f16x8 __attribute__((ext_vector_type(8)));
typedef float f32x4 __attribute__((ext_vector_type(4)));

#define TAU_Q 164           // ceil(5e-3 * 32768) = 10 sigma of 1-term fp16 dot noise (sigma~5e-4)
#define MASK_Q 2098790u     // (64.05)*32768: best-below -> rescue (masked-proto / all-negative guard)

typedef const __attribute__((address_space(1))) void gas_void;
typedef __attribute__((address_space(3))) void las_void;

__device__ __forceinline__ void gload_lds16(const void* g, void* l) {
  // async global->LDS DMA, 16B/lane; LDS dest = wave-uniform base + lane*16
  __builtin_amdgcn_global_load_lds((gas_void*)g, (las_void*)l, 16, 0, 0);
}

// ---------------- kernel 1: per-proto norm + fp16-hi pack ----------------
// q[m] = counts>0 ? 1/||p_m|| : 0. B-hat = fp16(P*q), packed so MFMA B-fragment
// (p16=m>>4, kc) at lane L sits at byte (p16*8+kc)*1024 + L*16 (coalesced 1KB chunks).
// Chunk property: protos [c*32,(c+1)*32) = bytes [c*16KB,(c+1)*16KB) -- contiguous.
__global__ __launch_bounds__(64) void prep_kernel(
    const float* __restrict__ P, const int* __restrict__ counts,
    float* __restrict__ q, int* __restrict__ wcount, f16x8* __restrict__ bhi) {
  const int m = blockIdx.x, lane = threadIdx.x;
  if (m == 0 && lane == 0) *wcount = 0;
  float4 v = *reinterpret_cast<const float4*>(P + (size_t)m * 256 + lane * 4);
  float s = v.x * v.x + v.y * v.y + v.z * v.z + v.w * v.w;
  for (int off = 32; off > 0; off >>= 1) s += __shfl_xor(s, off, 64);
  const float qm = (counts[m] > 0) ? (1.0f / sqrtf(s)) : 0.0f;
  if (lane == 0) q[m] = qm;
  if (lane < 32) {
    const int kg = lane;  // 8 k-elements per lane
    const float* src = P + (size_t)m * 256 + kg * 8;
    float4 v0 = *reinterpret_cast<const float4*>(src);
    float4 v1 = *reinterpret_cast<const float4*>(src + 4);
    float pe[8] = {v0.x, v0.y, v0.z, v0.w, v1.x, v1.y, v1.z, v1.w};
    f16x8 hi;
#pragma unroll
    for (int t = 0; t < 8; ++t) hi[t] = (_Float16)(pe[t] * qm);
    const int dst = ((m >> 4) * 8 + (kg >> 2)) * 64 + (kg & 3) * 16 + (m & 15);
    bhi[dst] = hi;
  }
}

// ---------------- kernel 2: fp16 MFMA screen -- 32-rows/wave for 3 waves/SIMD occupancy ----
// 256 threads = 4 waves; wave w owns rows [w*32, w*32+32) and scans ALL 1024 protos. BM=128.
// A in VGPRs: a[2][8] = 64 regs (halved vs r22's 64-row waves -> per-wave state ~145 regs
// -> 3 blocks/CU = 12 waves/CU, 1.5x r22's residency; r22's books: MFMA floor 40K cyc/SIMD
// vs 137K measured = wave-stall-bound at 2 waves/SIMD). B: 32 chunks of 32 protos x full K
// (16KB, contiguous in bhi), dbuf 2x16KB = 32KB LDS, r21-proven ordering (stage buf^1 ->
// compute buf -> barrier). Waves own disjoint rows -> NO cross-wave epilogue merge.
__global__ __launch_bounds__(256) void screen_kernel(
    const float* __restrict__ E, const f16x8* __restrict__ bhi,
    int* __restrict__ out, int* __restrict__ wcount,
    int* __restrict__ wl, int wlcap) {
  __shared__ __align__(16) unsigned char ldsB[32768];  // 2 bufs x 16KB (16 chunks of 1KB)

  const int tid = threadIdx.x;
  const int wave = tid >> 6, lane = tid & 63;
  const int g = lane >> 4, c = lane & 15;
  const int blockRow = blockIdx.x * 128;
  const char* bhiB = (const char*)bhi;

  // ---- B stage: chunk ch (32 protos, full K) = contiguous 16KB; wave stages 4 fragments ----
  auto stageB = [&](int b, int ch) {
#pragma unroll
    for (int i = 0; i < 4; ++i) {
      const int j = wave * 4 + i;  // fragment 0..15 within chunk
      gload_lds16(bhiB + ((size_t)ch << 14) + ((size_t)j << 10) + (size_t)lane * 16,
                  (char*)ldsB + (b << 14) + (j << 10));
    }
  };

  stageB(0, 0);  // latency hides under the A load+convert below

  // ---- load A into registers: wave's 32 rows x K=256, f32 -> hi fp16, fragment layout ----
  // a[fr][kc] elem t = E[blockRow + wave*32 + fr*16 + c][kc*32 + g*8 + t]
  f16x8 a[2][8];
#pragma unroll
  for (int fr = 0; fr < 2; ++fr) {
    const float* rowp = E + (size_t)(blockRow + wave * 32 + fr * 16 + c) * 256 + g * 8;
#pragma unroll
    for (int kc = 0; kc < 8; ++kc) {
      const float* p = rowp + kc * 32;
      float4 v0 = *reinterpret_cast<const float4*>(p);
      float4 v1 = *reinterpret_cast<const float4*>(p + 4);
      f16x8 h;
      h[0] = (_Float16)v0.x; h[1] = (_Float16)v0.y;
      h[2] = (_Float16)v0.z; h[3] = (_Float16)v0.w;
      h[4] = (_Float16)v1.x; h[5] = (_Float16)v1.y;
      h[6] = (_Float16)v1.z; h[7] = (_Float16)v1.w;
      a[fr][kc] = h;
    }
  }
  __syncthreads();  // drains chunk-0 DMA (and syncs the block)

  // quantized top-2 per lane: 8 row-slots (row = wave*32 + (s>>2)*16 + g*4 + (s&3))
  unsigned t1[8], t2[8];
#pragma unroll
  for (int s = 0; s < 8; ++s) { t1[s] = 0u; t2[s] = 0u; }

#pragma unroll 1
  for (int ch = 0; ch < 32; ++ch) {
    const int buf = ch & 1;
    if (ch < 31) stageB(buf ^ 1, ch + 1);  // buf^1's readers finished at prior barrier

    f32x4 acc[2][2];
#pragma unroll
    for (int fr = 0; fr < 2; ++fr)
#pragma unroll
      for (int fc = 0; fc < 2; ++fc) acc[fr][fc] = (f32x4){0.f, 0.f, 0.f, 0.f};

#pragma unroll
    for (int kc = 0; kc < 8; ++kc) {
      f16x8 bf[2];
#pragma unroll
      for (int fc = 0; fc < 2; ++fc) {
        const int j = fc * 8 + kc;  // fragment (p16 = 2ch+fc), this kc
        bf[fc] = *reinterpret_cast<const f16x8*>(
            (const char*)ldsB + (buf << 14) + (j << 10) + (size_t)lane * 16);
      }
#pragma unroll
      for (int fr = 0; fr < 2; ++fr)
#pragma unroll
        for (int fc = 0; fc < 2; ++fc)
          acc[fr][fc] = __builtin_amdgcn_mfma_f32_16x16x32_f16(a[fr][kc], bf[fc], acc[fr][fc], 0, 0, 0);
    }

    // ---- fold this chunk's 32 proto-columns into quantized top-2 ----
#pragma unroll
    for (int fc = 0; fc < 2; ++fc) {
      const unsigned mp = (unsigned)(1023 - (ch * 32 + fc * 16 + c));
#pragma unroll
      for (int fr = 0; fr < 2; ++fr)
#pragma unroll
        for (int reg = 0; reg < 4; ++reg) {
          const int s = fr * 4 + reg;
          const float v = acc[fr][fc][reg];
          const unsigned k = ((unsigned)fmaf(v, 32768.0f, 2097152.0f) << 10) | mp;
          const unsigned lo = (k < t1[s]) ? k : t1[s];
          t1[s] = (k > t1[s]) ? k : t1[s];
          t2[s] = (lo > t2[s]) ? lo : t2[s];
        }
    }

    __syncthreads();  // readers of buf done + this iter's DMA (into buf^1) drained
  }

  // ---- cross-lane top-2 merge over the 16 c-lanes sharing each row ----
#pragma unroll
  for (int s = 0; s < 8; ++s) {
#pragma unroll
    for (int off = 1; off <= 8; off <<= 1) {
      const unsigned o1 = (unsigned)__shfl_xor((int)t1[s], off);
      const unsigned o2 = (unsigned)__shfl_xor((int)t2[s], off);
      const unsigned lo = (o1 < t1[s]) ? o1 : t1[s];
      t1[s] = (o1 > t1[s]) ? o1 : t1[s];
      const unsigned hi2 = (o2 > t2[s]) ? o2 : t2[s];
      t2[s] = (lo > hi2) ? lo : hi2;
    }
  }

  // ---- direct writes: wave owns its 32 rows outright (no cross-wave merge) ----
  if (c == 0) {
#pragma unroll
    for (int s = 0; s < 8; ++s) {
      const int grow = blockRow + wave * 32 + (s >> 2) * 16 + g * 4 + (s & 3);
      const unsigned T1 = t1[s], T2 = t2[s];
      out[grow] = 1023 - (int)(T1 & 1023u);
      const unsigned iq1 = T1 >> 10, iq2 = T2 >> 10;
      if ((int)(iq1 - iq2) < TAU_Q || iq1 < MASK_Q) {
        const int p = atomicAdd(wcount, 1);
        if (p < wlcap) wl[p] = grow;
      }
    }
  }
}

// ---------------- kernel 3: exact f32 rescue -- 4 rows/batch, 512 grid-stride blocks --------
// Accumulation BIT-IDENTICAL to round-1: per (row, proto) one ascending-k fmaf chain
// (k4 ascending; x,y,z,w within each float4), then v = acc*q, strict > with lowest-m ties.
__global__ __launch_bounds__(256) void rescue_kernel(
    const float* __restrict__ E, const float* __restrict__ P,
    const float* __restrict__ q, int* __restrict__ out,
    const int* __restrict__ wcount, const int* __restrict__ wl, int wlcap) {
  __shared__ float Elds[4][260];
  __shared__ int rowsS[4];
  __shared__ float wv[4][4];
  __shared__ int wm[4][4];

  const int tid = threadIdx.x;
  const int wave = tid >> 6, lane = tid & 63;
  int total = *wcount;
  if (total > wlcap) total = wlcap;

  for (int b0 = blockIdx.x * 4; b0 < total; b0 += gridDim.x * 4) {
    const int nb = min(4, total - b0);
    __syncthreads();
    if (tid < 4) rowsS[tid] = wl[b0 + (tid < nb ? tid : 0)];
    __syncthreads();
    {  // stage E: 4 rows x 64 float4 = 256 units (one per thread)
      const int r = tid >> 6, k4 = tid & 63;
      *reinterpret_cast<float4*>(&Elds[r][k4 * 4]) =
          *reinterpret_cast<const float4*>(E + (size_t)rowsS[r] * 256 + k4 * 4);
    }
    __syncthreads();

    float acc[4][4];  // [row][proto j]; m = tid + 256*j
#pragma unroll
    for (int r = 0; r < 4; ++r)
#pragma unroll
      for (int j = 0; j < 4; ++j) acc[r][j] = 0.f;

#pragma unroll 4
    for (int k4 = 0; k4 < 64; ++k4) {
      float4 pv[4];
#pragma unroll
      for (int j = 0; j < 4; ++j)
        pv[j] = *reinterpret_cast<const float4*>(P + (size_t)(tid + 256 * j) * 256 + k4 * 4);
      float4 ev[4];
#pragma unroll
      for (int r = 0; r < 4; ++r) ev[r] = *reinterpret_cast<const float4*>(&Elds[r][k4 * 4]);
#pragma unroll
      for (int r = 0; r < 4; ++r)
#pragma unroll
        for (int j = 0; j < 4; ++j) {
          float a = acc[r][j];
          a = fmaf(pv[j].x, ev[r].x, a);
          a = fmaf(pv[j].y, ev[r].y, a);
          a = fmaf(pv[j].z, ev[r].z, a);
          a = fmaf(pv[j].w, ev[r].w, a);
          acc[r][j] = a;
        }
    }

    float qv[4];
#pragma unroll
    for (int j = 0; j < 4; ++j) qv[j] = q[tid + 256 * j];

#pragma unroll
    for (int r = 0; r < 4; ++r) {
      float bv = -3.0e38f;
      int bm = 0;
#pragma unroll
      for (int j = 0; j < 4; ++j) {  // m ascending -> strict > keeps lowest m
        const float v = (qv[j] > 0.f) ? acc[r][j] * qv[j] : -1.0e30f;
        if (v > bv) { bv = v; bm = tid + 256 * j; }
      }
#pragma unroll
      for (int off = 1; off <= 32; off <<= 1) {
        const float ov = __shfl_xor(bv, off);
        const int om = __shfl_xor(bm, off);
        if (ov > bv || (ov == bv && om < bm)) { bv = ov; bm = om; }
      }
      if (lane == 0) { wv[r][wave] = bv; wm[r][wave] = bm; }
    }
    __syncthreads();
    if (tid < 4) {
      float bv = wv[tid][0];
      int bm = wm[tid][0];
#pragma unroll
      for (int w = 1; w < 4; ++w) {
        const float ov = wv[tid][w];
        const int om = wm[tid][w];
        if (ov > bv || (ov == bv && om < bm)) { bv = ov; bm = om; }
      }
      if (tid < nb) out[rowsS[tid]] = bm;
    }
    __syncthreads();
  }
}

extern "C" void kernel_launch(void* const* d_in, const int* in_sizes, int n_in,
                              void* d_out, int out_size, void* d_ws, size_t ws_size,
                              hipStream_t stream) {
  const float* E = (const float*)d_in[0];
  const float* P = (const float*)d_in[1];
  const int* counts = (const int*)d_in[2];
  const int M = in_sizes[2];            // 1024
  const int Dd = in_sizes[1] / M;       // 256
  const int N = in_sizes[0] / Dd;       // 65536
  int* out = (int*)d_out;

  // workspace: q (4KB) | wcount @4096 | bhi @8192 (512KB) | worklist @532480
  float* qv = (float*)d_ws;
  int* wcount = (int*)((char*)d_ws + 4096);
  f16x8* bhi = (f16x8*)((char*)d_ws + 8192);
  int* wl = (int*)((char*)d_ws + 8192 + 524288);
  long long cap = ((long long)ws_size - (8192 + 524288)) / 4;
  if (cap < 0) cap = 0;
  if (cap > N) cap = N;
  int wlcap = (int)cap;

  prep_kernel<<<M, 64, 0, stream>>>(P, counts, qv, wcount, bhi);
  screen_kernel<<<N / 128, 256, 0, stream>>>(E, bhi, out, wcount, wl, wlcap);
  rescue_kernel<<<512, 256, 0, stream>>>(E, P, qv, out, wcount, wl, wlcap);
}